// Round 9
// baseline (633.894 us; speedup 1.0000x reference)
//
#include <hip/hip_runtime.h>
#include <hip/hip_cooperative_groups.h>
#include <hip/hip_bf16.h>
#include <cmath>

namespace cg = cooperative_groups;

#define F_IN 128
#define HDIM 64
#define NPB 256          // nodes per bucket (node >> 8)
#define NCH 1024         // edge chunks in place phase
#define CAP 4800         // col capacity per bucket (mean 4096, +11 sigma)
#define CHMAX 1600       // chunk = ceil(1.6M/1024) = 1563

typedef __attribute__((ext_vector_type(8))) short bf16x8;
typedef __attribute__((ext_vector_type(4))) float f32x4;
typedef __attribute__((ext_vector_type(2))) float f32x2;

__device__ __forceinline__ float bf2f(unsigned short u) {
    union { unsigned int i; float f; } v; v.i = ((unsigned int)u) << 16; return v.f;
}
__device__ __forceinline__ unsigned short f2bf(float f) {
    __hip_bfloat16 h = __float2bfloat16(f);
    union { __hip_bfloat16 h; unsigned short u; } c; c.h = h; return c.u;
}
__device__ __forceinline__ unsigned char f2fp8(float f) {
    int p = __builtin_amdgcn_cvt_pk_fp8_f32(f, f, 0, false);
    return (unsigned char)(p & 0xff);
}
__device__ __forceinline__ void fp8x8_acc(uint2 v, float* a) {
    f32x2 f;
    f = __builtin_amdgcn_cvt_pk_f32_fp8(v.x, false); a[0] += f.x; a[1] += f.y;
    f = __builtin_amdgcn_cvt_pk_f32_fp8(v.x, true);  a[2] += f.x; a[3] += f.y;
    f = __builtin_amdgcn_cvt_pk_f32_fp8(v.y, false); a[4] += f.x; a[5] += f.y;
    f = __builtin_amdgcn_cvt_pk_f32_fp8(v.y, true);  a[6] += f.x; a[7] += f.y;
}
__device__ __forceinline__ void fp8x8_acc_m(uint2 v, float m, float* a) {
    f32x2 f;
    f = __builtin_amdgcn_cvt_pk_f32_fp8(v.x, false); a[0] = fmaf(f.x, m, a[0]); a[1] = fmaf(f.y, m, a[1]);
    f = __builtin_amdgcn_cvt_pk_f32_fp8(v.x, true);  a[2] = fmaf(f.x, m, a[2]); a[3] = fmaf(f.y, m, a[3]);
    f = __builtin_amdgcn_cvt_pk_f32_fp8(v.y, false); a[4] = fmaf(f.x, m, a[4]); a[5] = fmaf(f.y, m, a[5]);
    f = __builtin_amdgcn_cvt_pk_f32_fp8(v.y, true);  a[6] = fmaf(f.x, m, a[6]); a[7] = fmaf(f.y, m, a[7]);
}

// 8 lanes/slot, uint2 rows, 8-edge independent rounds; tail is ONE
// clamped+masked round (1 memory latency), no serial dependent chain.
__device__ __forceinline__ void gather_rows(const int* __restrict__ col,
                                            const uint2* __restrict__ xws,
                                            int L, int s, int end, float* a) {
    int e = s;
    for (; e + 8 <= end; e += 8) {
        uint2 v0 = xws[(size_t)col[e + 0] * 8 + L];
        uint2 v1 = xws[(size_t)col[e + 1] * 8 + L];
        uint2 v2 = xws[(size_t)col[e + 2] * 8 + L];
        uint2 v3 = xws[(size_t)col[e + 3] * 8 + L];
        uint2 v4 = xws[(size_t)col[e + 4] * 8 + L];
        uint2 v5 = xws[(size_t)col[e + 5] * 8 + L];
        uint2 v6 = xws[(size_t)col[e + 6] * 8 + L];
        uint2 v7 = xws[(size_t)col[e + 7] * 8 + L];
        fp8x8_acc(v0, a); fp8x8_acc(v1, a); fp8x8_acc(v2, a); fp8x8_acc(v3, a);
        fp8x8_acc(v4, a); fp8x8_acc(v5, a); fp8x8_acc(v6, a); fp8x8_acc(v7, a);
    }
    if (e < end) {
        int last = end - 1;
        uint2 v0 = xws[(size_t)col[e]                * 8 + L];
        uint2 v1 = xws[(size_t)col[min(e + 1, last)] * 8 + L];
        uint2 v2 = xws[(size_t)col[min(e + 2, last)] * 8 + L];
        uint2 v3 = xws[(size_t)col[min(e + 3, last)] * 8 + L];
        uint2 v4 = xws[(size_t)col[min(e + 4, last)] * 8 + L];
        uint2 v5 = xws[(size_t)col[min(e + 5, last)] * 8 + L];
        uint2 v6 = xws[(size_t)col[min(e + 6, last)] * 8 + L];
        uint2 v7 = xws[(size_t)col[min(e + 7, last)] * 8 + L];
        fp8x8_acc(v0, a);
        fp8x8_acc_m(v1, (e + 1 < end) ? 1.0f : 0.0f, a);
        fp8x8_acc_m(v2, (e + 2 < end) ? 1.0f : 0.0f, a);
        fp8x8_acc_m(v3, (e + 3 < end) ? 1.0f : 0.0f, a);
        fp8x8_acc_m(v4, (e + 4 < end) ? 1.0f : 0.0f, a);
        fp8x8_acc_m(v5, (e + 5 < end) ? 1.0f : 0.0f, a);
        fp8x8_acc_m(v6, (e + 6 < end) ? 1.0f : 0.0f, a);
        fp8x8_acc_m(v7, (e + 7 < end) ? 1.0f : 0.0f, a);
    }
}

struct GcnP {
    const float* x; const int* src; const int* dst; const int* batch;
    const float* W1; const float* b1; const float* W2; const float* b2;
    const float* Wl; const float* bl; float* out;
    float* dinv; int4* slot_hdr; int* gcnt; int* pairs; int* col;
    unsigned short* w1t; unsigned short* w2t;
    unsigned char* xws8; unsigned char* xws8b; unsigned short* xh2;
    int* gstart;
    int n, E, G, nbuk, nslots, chunk;
};

// LDS union across phases; max member = csr phase (22.8 KB) -> 4+ blocks/CU.
union SU {
    struct { int hist[512], cur[512], dch[CHMAX]; } p1;                            // 10.4 KB
    struct { int plds[CAP], dl[256], sc[256], cur[256], h64[64], s64[64]; } p2;    // 22.8 KB
    struct { unsigned short Ws[64 * 136]; } p3;                                    // 17.4 KB
    struct { unsigned short Ws[64 * 72], Hs[32 * 72]; int snode[32]; float sdinv[32]; } p4; // 14.2 KB
    struct { float red[4][HDIM]; } p6;                                             // 1 KB
};

__launch_bounds__(256, 4)
__global__ void gcn_fused(GcnP p) {
    cg::grid_group grid = cg::this_grid();
    __shared__ SU su;
    const int tid = threadIdx.x;
    const int nbuk = p.nbuk;

    // ---- phase 0: W transposes + graph bounds + zero gcnt ----
    {
        int total = F_IN * 64 + HDIM * 64 + (p.G + 1) + 512;
        for (int t = blockIdx.x * 256 + tid; t < total; t += gridDim.x * 256) {
            int u = t;
            if (u < F_IN * 64) { int c = u & 63, k = u >> 6; p.w1t[c * F_IN + k] = f2bf(p.W1[u]); continue; }
            u -= F_IN * 64;
            if (u < HDIM * 64) { int c = u & 63, k = u >> 6; p.w2t[c * HDIM + k] = f2bf(p.W2[u]); continue; }
            u -= HDIM * 64;
            if (u <= p.G) {
                int g = u, lo = 0, hi = p.n;
                while (lo < hi) { int mid = (lo + hi) >> 1; if (p.batch[mid] < g) lo = mid + 1; else hi = mid; }
                p.gstart[g] = lo;
                continue;
            }
            u -= p.G + 1;
            if (u < 512) p.gcnt[u] = 0;
        }
    }
    grid.sync();

    // ---- phase 1: histogram + place (dst chunk staged in LDS) ----
    for (int c = blockIdx.x; c < NCH; c += gridDim.x) {
        for (int i = tid; i < nbuk; i += 256) su.p1.hist[i] = 0;
        __syncthreads();
        int lo = c * p.chunk, hi = min(p.E, lo + p.chunk), m = hi - lo;
        for (int i = tid; i < m; i += 256) {
            int d = p.dst[lo + i];
            su.p1.dch[i] = d;
            atomicAdd(&su.p1.hist[d >> 8], 1);
        }
        __syncthreads();
        for (int i = tid; i < nbuk; i += 256) {
            int cc = su.p1.hist[i];
            su.p1.cur[i] = i * CAP + (cc ? atomicAdd(&p.gcnt[i], cc) : 0);
        }
        __syncthreads();
        for (int i = tid; i < m; i += 256) {
            int d = su.p1.dch[i];
            int pos = atomicAdd(&su.p1.cur[d >> 8], 1);
            p.pairs[pos] = (p.src[lo + i] << 8) | (d & 255);
        }
        __syncthreads();
    }
    grid.sync();

    // ---- phase 2: per-bucket CSR + degree-sorted slot headers ----
    for (int b = blockIdx.x; b < nbuk; b += gridDim.x) {
        int nlo = b << 8;
        int eb = b * CAP;
        int cnt = p.gcnt[b];
        su.p2.dl[tid] = 0;
        if (tid < 64) su.p2.h64[tid] = 0;
        __syncthreads();
        for (int i = tid; i < cnt; i += 256) {
            int v = p.pairs[eb + i];
            su.p2.plds[i] = v;
            atomicAdd(&su.p2.dl[v & 255], 1);
        }
        __syncthreads();
        int d0 = su.p2.dl[tid];
        su.p2.sc[tid] = d0;
        __syncthreads();
        for (int off = 1; off < 256; off <<= 1) {
            int a = (tid >= off) ? su.p2.sc[tid - off] : 0;
            __syncthreads();
            su.p2.sc[tid] += a;
            __syncthreads();
        }
        int excl = su.p2.sc[tid] - d0;
        int node = nlo + tid;
        float dv = rsqrtf((float)(d0 + 1));
        if (node < p.n) p.dinv[node] = dv;
        su.p2.cur[tid] = eb + excl;
        atomicAdd(&su.p2.h64[min(d0, 63)], 1);
        __syncthreads();
        if (tid == 0) { int run = 0; for (int i = 0; i < 64; ++i) { su.p2.s64[i] = run; run += su.p2.h64[i]; } }
        __syncthreads();
        if (tid < 64) su.p2.h64[tid] = 0;
        __syncthreads();
        {
            int bin = min(d0, 63);
            int pos = su.p2.s64[bin] + atomicAdd(&su.p2.h64[bin], 1);
            int4 hdr;
            hdr.x = (node < p.n) ? node : 0x7fffffff;
            hdr.y = eb + excl;
            hdr.z = d0;
            hdr.w = __float_as_int(dv);
            p.slot_hdr[nlo + pos] = hdr;
        }
        __syncthreads();
        for (int i = tid; i < cnt; i += 256) {
            unsigned int v = (unsigned int)su.p2.plds[i];
            int pos = atomicAdd(&su.p2.cur[v & 255], 1);
            p.col[pos] = (int)(v >> 8);
        }
        __syncthreads();
    }
    grid.sync();

    // ---- phase 3: matmul1 (direct-X A-fragments, W1 in LDS) -> fp8(xw*dinv) ----
    {
        int gMM = (p.n + 63) >> 6;
        int wave = tid >> 6, lane = tid & 63, q = lane >> 4, nn = lane & 15;
        for (int tile = blockIdx.x; tile < gMM; tile += gridDim.x) {
            for (int i = tid; i < 64 * 16; i += 256) {
                int r = i >> 4, ch = i & 15;
                *(bf16x8*)(su.p3.Ws + r * 136 + ch * 8) = ((const bf16x8*)p.w1t)[i];
            }
            __syncthreads();
            int rowbase = tile << 6;
            int arow = rowbase + wave * 16 + nn;
            bool rok = arow < p.n;
            const float* Xr = p.x + (size_t)arow * F_IN;
            f32x4 acc[4] = {{0,0,0,0},{0,0,0,0},{0,0,0,0},{0,0,0,0}};
#pragma unroll
            for (int s = 0; s < 4; ++s) {
                bf16x8 af;
                if (rok) {
                    float4 xa = *(const float4*)(Xr + s * 32 + q * 8);
                    float4 xb = *(const float4*)(Xr + s * 32 + q * 8 + 4);
                    af[0] = (short)f2bf(xa.x); af[1] = (short)f2bf(xa.y);
                    af[2] = (short)f2bf(xa.z); af[3] = (short)f2bf(xa.w);
                    af[4] = (short)f2bf(xb.x); af[5] = (short)f2bf(xb.y);
                    af[6] = (short)f2bf(xb.z); af[7] = (short)f2bf(xb.w);
                } else {
                    short z[8] = {0,0,0,0,0,0,0,0};
                    af = *(bf16x8*)z;
                }
#pragma unroll
                for (int cc = 0; cc < 4; ++cc) {
                    bf16x8 bfv = *(const bf16x8*)(su.p3.Ws + (cc * 16 + nn) * 136 + s * 32 + q * 8);
                    acc[cc] = __builtin_amdgcn_mfma_f32_16x16x32_bf16(af, bfv, acc[cc], 0, 0, 0);
                }
            }
#pragma unroll
            for (int r = 0; r < 4; ++r) {
                int row = rowbase + wave * 16 + q * 4 + r;
                if (row >= p.n) continue;
                float dvv = p.dinv[row];
#pragma unroll
                for (int cc = 0; cc < 4; ++cc)
                    p.xws8[(size_t)row * HDIM + cc * 16 + nn] = f2fp8(acc[cc][r] * dvv);
            }
            __syncthreads();
        }
    }
    grid.sync();

    // ---- phase 4: gather1 + fused matmul2 (W2 staged once per block) ----
    {
        for (int i = tid; i < 64 * 8; i += 256) {
            int r = i >> 3, ch = i & 7;
            *(bf16x8*)(su.p4.Ws + r * 72 + ch * 8) = ((const bf16x8*)p.w2t)[i];
        }
        __syncthreads();
        int ngroups = p.nslots >> 5;
        int ls = tid >> 3, L = tid & 7;
        int wave = tid >> 6, lane = tid & 63, q = lane >> 4, nn = lane & 15;
        int mt = wave & 1, nt0 = (wave >> 1) * 2;
        for (int grp = blockIdx.x; grp < ngroups; grp += gridDim.x) {
            int slot = (grp << 5) + ls;
            int node = 0x7fffffff;
            float dvv = 0.0f;
            float a[8] = {0, 0, 0, 0, 0, 0, 0, 0};
            {
                int4 hdr = p.slot_hdr[slot];
                node = hdr.x;
                if (node < p.n) {
                    dvv = __int_as_float(hdr.w);
                    fp8x8_acc(((const uint2*)p.xws8)[(size_t)node * 8 + L], a);
                    gather_rows(p.col, (const uint2*)p.xws8, L, hdr.y, hdr.y + hdr.z, a);
                }
            }
            if (L == 0) { su.p4.snode[ls] = node; su.p4.sdinv[ls] = dvv; }
            {
                int f0 = L * 8;
                bf16x8 o;
                if (node < p.n) {
#pragma unroll
                    for (int j = 0; j < 8; ++j)
                        o[j] = (short)f2bf(fmaxf(fmaf(a[j], dvv, p.b1[f0 + j]), 0.0f));
                } else {
                    short z[8] = {0,0,0,0,0,0,0,0};
                    o = *(bf16x8*)z;
                }
                *(bf16x8*)(su.p4.Hs + ls * 72 + L * 8) = o;
            }
            __syncthreads();
            f32x4 acc2[2] = {{0,0,0,0},{0,0,0,0}};
#pragma unroll
            for (int s = 0; s < 2; ++s) {
                bf16x8 af = *(const bf16x8*)(su.p4.Hs + (mt * 16 + nn) * 72 + s * 32 + q * 8);
#pragma unroll
                for (int t = 0; t < 2; ++t) {
                    bf16x8 bfv = *(const bf16x8*)(su.p4.Ws + ((nt0 + t) * 16 + nn) * 72 + s * 32 + q * 8);
                    acc2[t] = __builtin_amdgcn_mfma_f32_16x16x32_bf16(af, bfv, acc2[t], 0, 0, 0);
                }
            }
#pragma unroll
            for (int r = 0; r < 4; ++r) {
                int lslot = mt * 16 + q * 4 + r;
                int nd = su.p4.snode[lslot];
                if (nd >= p.n) continue;
                float dvr = su.p4.sdinv[lslot];
#pragma unroll
                for (int t = 0; t < 2; ++t)
                    p.xws8b[(size_t)nd * HDIM + (nt0 + t) * 16 + nn] = f2fp8(acc2[t][r] * dvr);
            }
            __syncthreads();
        }
    }
    grid.sync();

    // ---- phase 5: gather2 -> bf16 h2 (pure, no LDS) ----
    {
        int tot = p.nslots * 8;
        for (int t5 = blockIdx.x * 256 + tid; t5 < tot; t5 += gridDim.x * 256) {
            int slot = t5 >> 3, L = t5 & 7;
            int4 hdr = p.slot_hdr[slot];
            int node = hdr.x;
            if (node < p.n) {
                float dvv = __int_as_float(hdr.w);
                float a[8] = {0, 0, 0, 0, 0, 0, 0, 0};
                fp8x8_acc(((const uint2*)p.xws8b)[(size_t)node * 8 + L], a);
                gather_rows(p.col, (const uint2*)p.xws8b, L, hdr.y, hdr.y + hdr.z, a);
                int f0 = L * 8;
                bf16x8 o;
#pragma unroll
                for (int j = 0; j < 8; ++j)
                    o[j] = (short)f2bf(fmaxf(fmaf(a[j], dvv, p.b2[f0 + j]), 0.0f));
                ((bf16x8*)p.xh2)[(size_t)node * 8 + L] = o;
            }
        }
    }
    grid.sync();

    // ---- phase 6: mean-pool + head + sigmoid ----
    {
        int f = tid & 63, rg = tid >> 6;
        for (int g = blockIdx.x; g < p.G; g += gridDim.x) {
            int s = p.gstart[g], e = p.gstart[g + 1];
            float acc = 0.0f;
            for (int i = s + rg; i < e; i += 4)
                acc += bf2f(p.xh2[(size_t)i * HDIM + f]);
            su.p6.red[rg][f] = acc;
            __syncthreads();
            if (rg == 0) {
                float v = (su.p6.red[0][f] + su.p6.red[1][f]) + (su.p6.red[2][f] + su.p6.red[3][f]);
                float c = fmaxf((float)(e - s), 1.0f);
                v = v * p.Wl[f] * (1.0f / c);
#pragma unroll
                for (int off = 32; off; off >>= 1) v += __shfl_down(v, off, 64);
                if (f == 0) p.out[g] = 1.0f / (1.0f + expf(-(v + p.bl[0])));
            }
            __syncthreads();
        }
    }
}

// ---------------- launch ----------------

extern "C" void kernel_launch(void* const* d_in, const int* in_sizes, int n_in,
                              void* d_out, int out_size, void* d_ws, size_t ws_size,
                              hipStream_t stream) {
    const float* x   = (const float*)d_in[0];
    const int* ei    = (const int*)d_in[1];
    const int* batch = (const int*)d_in[2];
    const float* W1  = (const float*)d_in[3];
    const float* b1  = (const float*)d_in[4];
    const float* W2  = (const float*)d_in[5];
    const float* b2  = (const float*)d_in[6];
    const float* Wl  = (const float*)d_in[7];
    const float* bl  = (const float*)d_in[8];
    float* out = (float*)d_out;

    const int n = in_sizes[0] / F_IN;   // 100000
    const int E = in_sizes[1] / 2;      // 1600000
    const int G = out_size;             // 512

    int nbuk = (n + NPB - 1) / NPB;     // 391
    int nslots = nbuk * NPB;            // 100096

    // workspace layout
    char* wsb = (char*)d_ws;
    auto alloc = [&](size_t bytes) { char* p = wsb; wsb += (bytes + 255) & ~(size_t)255; return p; };
    float* dinv       = (float*)alloc((size_t)n * 4);
    int4*  slot_hdr   = (int4*)alloc((size_t)nslots * 16);
    int*   gcnt       = (int*)alloc(512 * 4);
    int*   pairs      = (int*)alloc((size_t)nbuk * CAP * 4);
    int*   colx       = (int*)alloc((size_t)nbuk * CAP * 4);
    unsigned short* w1t  = (unsigned short*)alloc((size_t)F_IN * HDIM * 2);
    unsigned short* w2t  = (unsigned short*)alloc((size_t)HDIM * HDIM * 2);
    unsigned char*  xws8 = (unsigned char*)alloc((size_t)n * HDIM);       // fp8 payload L1
    unsigned char*  xws8b= (unsigned char*)alloc((size_t)n * HDIM);       // fp8 payload L2
    unsigned short* xh2  = (unsigned short*)alloc((size_t)n * HDIM * 2);  // layer-2 h (bf16)
    int*   gstart     = (int*)alloc(((size_t)G + 1) * 4);

    GcnP prm;
    prm.x = x; prm.src = ei; prm.dst = ei + E; prm.batch = batch;
    prm.W1 = W1; prm.b1 = b1; prm.W2 = W2; prm.b2 = b2; prm.Wl = Wl; prm.bl = bl;
    prm.out = out;
    prm.dinv = dinv; prm.slot_hdr = slot_hdr; prm.gcnt = gcnt;
    prm.pairs = pairs; prm.col = colx;
    prm.w1t = w1t; prm.w2t = w2t;
    prm.xws8 = xws8; prm.xws8b = xws8b; prm.xh2 = xh2;
    prm.gstart = gstart;
    prm.n = n; prm.E = E; prm.G = G; prm.nbuk = nbuk; prm.nslots = nslots;
    prm.chunk = (E + NCH - 1) / NCH;    // 1563 <= CHMAX

    // co-residency-safe grid (cached): blocks/CU from occupancy query x CU count
    static int s_grid = 0;
    if (s_grid == 0) {
        int maxb = 0;
        hipOccupancyMaxActiveBlocksPerMultiprocessor(&maxb, (const void*)gcn_fused, 256, 0);
        if (maxb < 1) maxb = 1;
        int ncu = 256;
        int dev = 0;
        hipDeviceProp_t prop;
        if (hipGetDevice(&dev) == hipSuccess &&
            hipGetDeviceProperties(&prop, dev) == hipSuccess &&
            prop.multiProcessorCount > 0)
            ncu = prop.multiProcessorCount;
        long g = (long)maxb * (long)ncu;
        if (g > 2048) g = 2048;
        if (g < 256)  g = 256;
        s_grid = (int)g;
    }

    void* kargs[] = { (void*)&prm };
    hipLaunchCooperativeKernel((void*)gcn_fused, dim3(s_grid), dim3(256), kargs, 0, stream);
}

// Round 10
// 229.868 us; speedup vs baseline: 2.7576x; 2.7576x over previous
//
#include <hip/hip_runtime.h>
#include <hip/hip_bf16.h>
#include <cmath>

#define F_IN 128
#define HDIM 64
#define NPB 512          // nodes per bucket (node >> 9)
#define NB1 512          // edge chunks for the place kernel
#define CAP 9216         // col capacity per bucket (mean 8192, +11 sigma)
#define CHMAX 3136       // max chunk size staged in LDS (chunk = 3125)

typedef __attribute__((ext_vector_type(8))) short bf16x8;
typedef __attribute__((ext_vector_type(4))) float f32x4;
typedef __attribute__((ext_vector_type(2))) float f32x2;

__device__ __forceinline__ float bf2f(unsigned short u) {
    union { unsigned int i; float f; } v; v.i = ((unsigned int)u) << 16; return v.f;
}
__device__ __forceinline__ unsigned short f2bf(float f) {
    __hip_bfloat16 h = __float2bfloat16(f);
    union { __hip_bfloat16 h; unsigned short u; } c; c.h = h; return c.u;
}
__device__ __forceinline__ unsigned char f2fp8(float f) {
    int p = __builtin_amdgcn_cvt_pk_fp8_f32(f, f, 0, false);
    return (unsigned char)(p & 0xff);
}
__device__ __forceinline__ void fp8x8_acc(uint2 v, float* a) {
    f32x2 f;
    f = __builtin_amdgcn_cvt_pk_f32_fp8(v.x, false); a[0] += f.x; a[1] += f.y;
    f = __builtin_amdgcn_cvt_pk_f32_fp8(v.x, true);  a[2] += f.x; a[3] += f.y;
    f = __builtin_amdgcn_cvt_pk_f32_fp8(v.y, false); a[4] += f.x; a[5] += f.y;
    f = __builtin_amdgcn_cvt_pk_f32_fp8(v.y, true);  a[6] += f.x; a[7] += f.y;
}
__device__ __forceinline__ void fp8x8_acc_m(uint2 v, float m, float* a) {
    f32x2 f;
    f = __builtin_amdgcn_cvt_pk_f32_fp8(v.x, false); a[0] = fmaf(f.x, m, a[0]); a[1] = fmaf(f.y, m, a[1]);
    f = __builtin_amdgcn_cvt_pk_f32_fp8(v.x, true);  a[2] = fmaf(f.x, m, a[2]); a[3] = fmaf(f.y, m, a[3]);
    f = __builtin_amdgcn_cvt_pk_f32_fp8(v.y, false); a[4] = fmaf(f.x, m, a[4]); a[5] = fmaf(f.y, m, a[5]);
    f = __builtin_amdgcn_cvt_pk_f32_fp8(v.y, true);  a[6] = fmaf(f.x, m, a[6]); a[7] = fmaf(f.y, m, a[7]);
}

// Gather: 8 lanes/slot, uint2 rows, 8-edge independent rounds; tail is ONE
// clamped+masked round (1 memory latency) instead of a serial dependent chain.
__device__ __forceinline__ void gather_rows(const int* __restrict__ col,
                                            const uint2* __restrict__ xws,
                                            int L, int s, int end, float* a) {
    int e = s;
    for (; e + 8 <= end; e += 8) {
        uint2 v0 = xws[(size_t)col[e + 0] * 8 + L];
        uint2 v1 = xws[(size_t)col[e + 1] * 8 + L];
        uint2 v2 = xws[(size_t)col[e + 2] * 8 + L];
        uint2 v3 = xws[(size_t)col[e + 3] * 8 + L];
        uint2 v4 = xws[(size_t)col[e + 4] * 8 + L];
        uint2 v5 = xws[(size_t)col[e + 5] * 8 + L];
        uint2 v6 = xws[(size_t)col[e + 6] * 8 + L];
        uint2 v7 = xws[(size_t)col[e + 7] * 8 + L];
        fp8x8_acc(v0, a); fp8x8_acc(v1, a); fp8x8_acc(v2, a); fp8x8_acc(v3, a);
        fp8x8_acc(v4, a); fp8x8_acc(v5, a); fp8x8_acc(v6, a); fp8x8_acc(v7, a);
    }
    if (e < end) {
        int last = end - 1;
        uint2 v0 = xws[(size_t)col[e]               * 8 + L];
        uint2 v1 = xws[(size_t)col[min(e + 1, last)] * 8 + L];
        uint2 v2 = xws[(size_t)col[min(e + 2, last)] * 8 + L];
        uint2 v3 = xws[(size_t)col[min(e + 3, last)] * 8 + L];
        uint2 v4 = xws[(size_t)col[min(e + 4, last)] * 8 + L];
        uint2 v5 = xws[(size_t)col[min(e + 5, last)] * 8 + L];
        uint2 v6 = xws[(size_t)col[min(e + 6, last)] * 8 + L];
        uint2 v7 = xws[(size_t)col[min(e + 7, last)] * 8 + L];
        fp8x8_acc(v0, a);
        fp8x8_acc_m(v1, (e + 1 < end) ? 1.0f : 0.0f, a);
        fp8x8_acc_m(v2, (e + 2 < end) ? 1.0f : 0.0f, a);
        fp8x8_acc_m(v3, (e + 3 < end) ? 1.0f : 0.0f, a);
        fp8x8_acc_m(v4, (e + 4 < end) ? 1.0f : 0.0f, a);
        fp8x8_acc_m(v5, (e + 5 < end) ? 1.0f : 0.0f, a);
        fp8x8_acc_m(v6, (e + 6 < end) ? 1.0f : 0.0f, a);
        fp8x8_acc_m(v7, (e + 7 < end) ? 1.0f : 0.0f, a);
    }
}

// ========== K1: init — W transposes + graph bounds + zero gcnt ==========

__launch_bounds__(256)
__global__ void k_init(const float* __restrict__ W1, const float* __restrict__ W2,
                       unsigned short* __restrict__ w1t, unsigned short* __restrict__ w2t,
                       const int* __restrict__ batch, int* __restrict__ gstart,
                       int n, int G, int* __restrict__ gcnt) {
    int t = blockIdx.x * 256 + threadIdx.x;
    if (t < F_IN * 64) {                       // w1t[c][k] = W1[k][c]
        int c = t & 63, k = t >> 6;
        w1t[c * F_IN + k] = f2bf(W1[t]);
        return;
    }
    t -= F_IN * 64;
    if (t < HDIM * 64) {                       // w2t[c][k] = W2[k][c]
        int c = t & 63, k = t >> 6;
        w2t[c * HDIM + k] = f2bf(W2[t]);
        return;
    }
    t -= HDIM * 64;
    if (t <= G) {                              // gstart: first node of graph t
        int g = t;
        int lo = 0, hi = n;
        while (lo < hi) {
            int mid = (lo + hi) >> 1;
            if (batch[mid] < g) lo = mid + 1; else hi = mid;
        }
        gstart[g] = lo;
        return;
    }
    t -= G + 1;
    if (t < 256) gcnt[t] = 0;
}

// ========== K2: fused histogram + place, 512-node buckets, 1024-thread blocks ==========
// dst chunk staged in LDS during the histogram pass and reused by the place
// pass (saves the 6.4 MB second HBM read + its dependent-load chain).
// Runs per (chunk,bucket) ~= 16 edges = 64B. 32 waves/CU at grid 512.

__launch_bounds__(1024)
__global__ void p_place(const int* __restrict__ src, const int* __restrict__ dst,
                        int* __restrict__ gcnt, int* __restrict__ pairs,
                        int E, int nbuk, int chunk) {
    __shared__ int hist[256];
    __shared__ int cur[256];
    __shared__ int dch[CHMAX];
    int tid = threadIdx.x;
    for (int i = tid; i < nbuk; i += 1024) hist[i] = 0;
    __syncthreads();
    int lo = blockIdx.x * chunk, hi = min(E, lo + chunk), m = hi - lo;
    for (int i = tid; i < m; i += 1024) {
        int d = dst[lo + i];
        dch[i] = d;
        atomicAdd(&hist[d >> 9], 1);
    }
    __syncthreads();
    for (int i = tid; i < nbuk; i += 1024) {
        int c = hist[i];
        cur[i] = i * CAP + (c ? atomicAdd(&gcnt[i], c) : 0);
    }
    __syncthreads();
    for (int i = tid; i < m; i += 1024) {
        int d = dch[i];
        int pos = atomicAdd(&cur[d >> 9], 1);
        pairs[pos] = (src[lo + i] << 9) | (d & 511);
    }
}

// ========== K3: per-bucket local CSR (512 nodes, LDS-staged) + degree-sorted headers ==========

__launch_bounds__(512)
__global__ void p2_csr(const int* __restrict__ pairs, const int* __restrict__ bucket_cnt,
                       float* __restrict__ dinv, int* __restrict__ col,
                       int4* __restrict__ slot_hdr, int n) {
    __shared__ int plds[CAP];
    __shared__ int dl[512];
    __shared__ int sc[512];
    __shared__ int cur[512];
    __shared__ int h64[64];
    __shared__ int s64[64];
    int b = blockIdx.x, tid = threadIdx.x;
    int nlo = b << 9;
    int eb = b * CAP;
    int cnt = bucket_cnt[b];
    dl[tid] = 0;
    if (tid < 64) h64[tid] = 0;
    __syncthreads();
    for (int i = tid; i < cnt; i += 512) {
        int v = pairs[eb + i];
        plds[i] = v;
        atomicAdd(&dl[v & 511], 1);
    }
    __syncthreads();
    int d0 = dl[tid];
    sc[tid] = d0;
    __syncthreads();
    for (int off = 1; off < 512; off <<= 1) {
        int a = (tid >= off) ? sc[tid - off] : 0;
        __syncthreads();
        sc[tid] += a;
        __syncthreads();
    }
    int excl = sc[tid] - d0;
    int node = nlo + tid;
    float dv = rsqrtf((float)(d0 + 1));
    if (node < n) dinv[node] = dv;
    cur[tid] = eb + excl;
    atomicAdd(&h64[min(d0, 63)], 1);
    __syncthreads();
    if (tid == 0) { int run = 0; for (int i = 0; i < 64; ++i) { s64[i] = run; run += h64[i]; } }
    __syncthreads();
    if (tid < 64) h64[tid] = 0;
    __syncthreads();
    {
        int bin = min(d0, 63);
        int pos = s64[bin] + atomicAdd(&h64[bin], 1);
        int4 hdr;
        hdr.x = (node < n) ? node : 0x7fffffff;
        hdr.y = eb + excl;
        hdr.z = d0;
        hdr.w = __float_as_int(dv);
        slot_hdr[nlo + pos] = hdr;
    }
    __syncthreads();
    for (int i = tid; i < cnt; i += 512) {
        unsigned int v = (unsigned int)plds[i];
        int pos = atomicAdd(&cur[v & 511], 1);
        col[pos] = (int)(v >> 9);
    }
}

// ========== K4: matmul1 (f32 X, K=128) -> fp8(xw * dinv) ==========

template <int K>
__launch_bounds__(256)
__global__ void matmul_mfma(const float* __restrict__ X, const unsigned short* __restrict__ Wt,
                            const float* __restrict__ dinv, unsigned char* __restrict__ out,
                            int n) {
    constexpr int KS  = K / 32;
    constexpr int LDX = K + 8;
    __shared__ unsigned short Xs[64 * LDX];
    __shared__ unsigned short Ws[64 * LDX];
    int tid = threadIdx.x;
    int rowbase = blockIdx.x * 64;
    for (int i = tid; i < 64 * (K / 8); i += 256) {
        int r = i / (K / 8), ch = i % (K / 8);
        *(bf16x8*)(Ws + r * LDX + ch * 8) = ((const bf16x8*)Wt)[i];
    }
    {
        const float4* X4 = (const float4*)X;
        for (int i = tid; i < 64 * (K / 4); i += 256) {
            int r = i / (K / 4), k4 = i % (K / 4);
            ushort4 u = { 0, 0, 0, 0 };
            int gr = rowbase + r;
            if (gr < n) {
                float4 v = X4[(size_t)gr * (K / 4) + k4];
                u.x = f2bf(v.x); u.y = f2bf(v.y); u.z = f2bf(v.z); u.w = f2bf(v.w);
            }
            *(ushort4*)(Xs + r * LDX + k4 * 4) = u;
        }
    }
    __syncthreads();
    int wave = tid >> 6, lane = tid & 63;
    int q = lane >> 4, nn = lane & 15;
    f32x4 acc[4] = {{0,0,0,0},{0,0,0,0},{0,0,0,0},{0,0,0,0}};
    int mrow = wave * 16 + nn;
#pragma unroll
    for (int s = 0; s < KS; ++s) {
        bf16x8 af = *(const bf16x8*)(Xs + mrow * LDX + s * 32 + q * 8);
#pragma unroll
        for (int c = 0; c < 4; ++c) {
            bf16x8 bf = *(const bf16x8*)(Ws + (c * 16 + nn) * LDX + s * 32 + q * 8);
            acc[c] = __builtin_amdgcn_mfma_f32_16x16x32_bf16(af, bf, acc[c], 0, 0, 0);
        }
    }
#pragma unroll
    for (int r = 0; r < 4; ++r) {
        int row = rowbase + wave * 16 + q * 4 + r;
        if (row >= n) continue;
        float dv = dinv[row];
#pragma unroll
        for (int c = 0; c < 4; ++c)
            out[(size_t)row * HDIM + c * 16 + nn] = f2fp8(acc[c][r] * dv);
    }
}

// ========== K5: gather1 + fused matmul2 (32-slot blocks) ==========

__launch_bounds__(256)
__global__ void gather1_mm2(const int4* __restrict__ slot_hdr, const int* __restrict__ col,
                            const uint2* __restrict__ xws, const float* __restrict__ bias,
                            const unsigned short* __restrict__ w2t,
                            unsigned char* __restrict__ out8, int nslots, int n) {
    __shared__ unsigned short Hs[32 * 72];   // h1 tile, bf16, row stride 72
    __shared__ unsigned short Ws[64 * 72];   // W2^T rows: Ws[c][k]
    __shared__ int   snode[32];
    __shared__ float sdinv[32];

    int tid = threadIdx.x;
    int ls = tid >> 3;          // local slot 0..31
    int L  = tid & 7;           // feature-octet lane
    int slot = blockIdx.x * 32 + ls;

    for (int i = tid; i < 64 * 8; i += 256) {
        int r = i >> 3, ch = i & 7;
        *(bf16x8*)(Ws + r * 72 + ch * 8) = ((const bf16x8*)w2t)[i];
    }

    // ---- gather phase ----
    int node = 0x7fffffff;
    float dv = 0.0f;
    float a[8] = {0, 0, 0, 0, 0, 0, 0, 0};
    if (slot < nslots) {
        int4 hdr = slot_hdr[slot];
        node = hdr.x;
        if (node < n) {
            dv = __int_as_float(hdr.w);
            fp8x8_acc(xws[(size_t)node * 8 + L], a);   // self-loop term
            gather_rows(col, xws, L, hdr.y, hdr.y + hdr.z, a);
        }
    }
    if (L == 0) { snode[ls] = node; sdinv[ls] = dv; }
    {
        int f0 = L * 8;
        bf16x8 o;
        if (node < n) {
#pragma unroll
            for (int j = 0; j < 8; ++j)
                o[j] = (short)f2bf(fmaxf(fmaf(a[j], dv, bias[f0 + j]), 0.0f));
        } else {
            short z[8] = {0,0,0,0,0,0,0,0};
            o = *(bf16x8*)z;
        }
        *(bf16x8*)(Hs + ls * 72 + L * 8) = o;
    }
    __syncthreads();

    // ---- matmul2 phase: D[32x64] = Hs @ W2, scaled by sdinv, emit fp8 ----
    int wave = tid >> 6, lane = tid & 63;
    int q = lane >> 4, nn = lane & 15;
    int mt  = wave & 1;          // M-tile (rows 0-15 / 16-31)
    int nt0 = (wave >> 1) * 2;   // N-tiles {nt0, nt0+1}
    f32x4 acc[2] = {{0,0,0,0},{0,0,0,0}};
#pragma unroll
    for (int s = 0; s < 2; ++s) {
        bf16x8 af = *(const bf16x8*)(Hs + (mt * 16 + nn) * 72 + s * 32 + q * 8);
#pragma unroll
        for (int t = 0; t < 2; ++t) {
            bf16x8 bf = *(const bf16x8*)(Ws + ((nt0 + t) * 16 + nn) * 72 + s * 32 + q * 8);
            acc[t] = __builtin_amdgcn_mfma_f32_16x16x32_bf16(af, bf, acc[t], 0, 0, 0);
        }
    }
#pragma unroll
    for (int r = 0; r < 4; ++r) {
        int lslot = mt * 16 + q * 4 + r;
        int nd = snode[lslot];
        if (nd >= n) continue;
        float dvr = sdinv[lslot];
#pragma unroll
        for (int t = 0; t < 2; ++t)
            out8[(size_t)nd * HDIM + (nt0 + t) * 16 + nn] = f2fp8(acc[t][r] * dvr);
    }
}

// ========== K6: gather2 — pure, barrier-free -> bf16 h2 ==========

__launch_bounds__(256)
__global__ void csr_gather8_fp8(const int4* __restrict__ slot_hdr, const int* __restrict__ col,
                                const uint2* __restrict__ xws, const float* __restrict__ bias,
                                bf16x8* __restrict__ outb, int nslots, int n) {
    int t = blockIdx.x * 256 + threadIdx.x;
    int slot = t >> 3;
    if (slot >= nslots) return;
    int L = t & 7;
    int4 hdr = slot_hdr[slot];
    int node = hdr.x;
    if (node >= n) return;
    float dv = __int_as_float(hdr.w);

    float a[8] = {0, 0, 0, 0, 0, 0, 0, 0};
    fp8x8_acc(xws[(size_t)node * 8 + L], a);
    gather_rows(col, xws, L, hdr.y, hdr.y + hdr.z, a);

    int f0 = L * 8;
    bf16x8 o;
#pragma unroll
    for (int j = 0; j < 8; ++j)
        o[j] = (short)f2bf(fmaxf(fmaf(a[j], dv, bias[f0 + j]), 0.0f));
    outb[(size_t)node * 8 + L] = o;
}

// ========== K7: mean-pool (bf16 rows) + head + sigmoid ==========

__launch_bounds__(256)
__global__ void pool_head(const unsigned short* __restrict__ h, const int* __restrict__ gstart,
                          const float* __restrict__ Wl, const float* __restrict__ bl,
                          float* __restrict__ out, int G) {
    int g = blockIdx.x;
    int s = gstart[g], e = gstart[g + 1];
    int f  = threadIdx.x & 63;
    int rg = threadIdx.x >> 6;
    float acc = 0.0f;
    for (int i = s + rg; i < e; i += 4)
        acc += bf2f(h[(size_t)i * HDIM + f]);
    __shared__ float red[4][HDIM];
    red[rg][f] = acc;
    __syncthreads();
    if (rg == 0) {
        float v = (red[0][f] + red[1][f]) + (red[2][f] + red[3][f]);
        float c = fmaxf((float)(e - s), 1.0f);
        v = v * Wl[f] * (1.0f / c);
#pragma unroll
        for (int off = 32; off; off >>= 1) v += __shfl_down(v, off, 64);
        if (f == 0) out[g] = 1.0f / (1.0f + expf(-(v + bl[0])));
    }
}

// ---------------- launch ----------------

extern "C" void kernel_launch(void* const* d_in, const int* in_sizes, int n_in,
                              void* d_out, int out_size, void* d_ws, size_t ws_size,
                              hipStream_t stream) {
    const float* x   = (const float*)d_in[0];
    const int* ei    = (const int*)d_in[1];
    const int* batch = (const int*)d_in[2];
    const float* W1  = (const float*)d_in[3];
    const float* b1  = (const float*)d_in[4];
    const float* W2  = (const float*)d_in[5];
    const float* b2  = (const float*)d_in[6];
    const float* Wl  = (const float*)d_in[7];
    const float* bl  = (const float*)d_in[8];
    float* out = (float*)d_out;

    const int n = in_sizes[0] / F_IN;   // 100000
    const int E = in_sizes[1] / 2;      // 1600000
    const int G = out_size;             // 512

    const int* srcp = ei;
    const int* dstp = ei + E;

    int nbuk = (n + NPB - 1) / NPB;     // 196
    int nslots = nbuk * NPB;            // 100352

    // workspace layout
    char* wsb = (char*)d_ws;
    auto alloc = [&](size_t bytes) { char* p = wsb; wsb += (bytes + 255) & ~(size_t)255; return p; };
    float* dinv       = (float*)alloc((size_t)n * 4);
    int4*  slot_hdr   = (int4*)alloc((size_t)nslots * 16);
    int*   gcnt       = (int*)alloc(256 * 4);
    int*   pairs      = (int*)alloc((size_t)nbuk * CAP * 4);
    int*   colx       = (int*)alloc((size_t)nbuk * CAP * 4);
    unsigned short* w1t  = (unsigned short*)alloc((size_t)F_IN * HDIM * 2);
    unsigned short* w2t  = (unsigned short*)alloc((size_t)HDIM * HDIM * 2);
    unsigned char*  xws8 = (unsigned char*)alloc((size_t)n * HDIM);       // fp8 payload L1
    unsigned char*  xws8b= (unsigned char*)alloc((size_t)n * HDIM);       // fp8 payload L2
    unsigned short* xh2  = (unsigned short*)alloc((size_t)n * HDIM * 2);  // layer-2 h (bf16)
    int*   gstart     = (int*)alloc(((size_t)G + 1) * 4);

    const int TB = 256;
    int gMM  = (n + 63) / 64;                         // 1563
    int chunk = (E + NB1 - 1) / NB1;                  // 3125 <= CHMAX
    int gG8  = (nslots * 8 + TB - 1) / TB;            // 3136
    int gS   = (nslots + 31) / 32;                    // 3136
    int initWork = F_IN * 64 + HDIM * 64 + (G + 1) + 256;
    int gInit = (initWork + TB - 1) / TB;

    // init: transposes, graph bounds, zero gcnt
    k_init<<<gInit, TB, 0, stream>>>(W1, W2, w1t, w2t, batch, gstart, n, G, gcnt);
    // fused histogram + place: 512-node buckets, dst chunk staged in LDS
    p_place<<<NB1, 1024, 0, stream>>>(srcp, dstp, gcnt, pairs, E, nbuk, chunk);
    // per-bucket CSR (512 nodes/bucket, pairs staged through LDS)
    p2_csr<<<nbuk, 512, 0, stream>>>(pairs, gcnt, dinv, colx, slot_hdr, n);
    // layer 1 matmul -> fp8 scaled payload
    matmul_mfma<F_IN><<<gMM, TB, 0, stream>>>(x, w1t, dinv, xws8, n);
    // gather1 + fused matmul2 -> fp8 scaled layer-2 payload
    gather1_mm2<<<gS, TB, 0, stream>>>(slot_hdr, colx, (const uint2*)xws8,
                                       b1, w2t, xws8b, nslots, n);
    // gather2 -> bf16 h2 (pure, barrier-free)
    csr_gather8_fp8<<<gG8, TB, 0, stream>>>(slot_hdr, colx, (const uint2*)xws8b,
                                            b2, (bf16x8*)xh2, nslots, n);
    // pool + head
    pool_head<<<G, TB, 0, stream>>>(xh2, gstart, Wl, bl, out, G);
}